// Round 1
// baseline (1841.961 us; speedup 1.0000x reference)
//
#include <hip/hip_runtime.h>

// TensorProduct: out[n,p3,k,f] = sum_{i,j} cg[i,j,k] * x1[n,p1,i,f]*x2[n,p2,j,f]
// with parity coupling: even = eee+ooe, odd = eoo+oeo.
// Parity-Karatsuba: s = couple(a0+a1, b0+b1), d = couple(a0-a1, b0-b1)
//   out_even = (s+d)/2, out_odd = (s-d)/2   (0.5 folded into a-side prep)
// CG sparsity (triangle rule |l1-l2|<=l3<=l1+l2) is compile-time known:
// 1225 of 2025 entries; valid k range per (i,j) is contiguous -> scalar loads merge.

#define NN 50000
#define FF 128
#define NL1 9
#define NL2 9
#define NL3 25

__global__ __launch_bounds__(256) void tp_kernel(
    const float* __restrict__ x1, const float* __restrict__ x2,
    const float* __restrict__ cg, float* __restrict__ out) {
  // l value of each flattened (l,m) slot
  constexpr int LOF[9]  = {0,1,1,1,2,2,2,2,2};
  constexpr int LOF3[25] = {0,1,1,1,2,2,2,2,2,3,3,3,3,3,3,3,4,4,4,4,4,4,4,4,4};

  int tid = blockIdx.x * blockDim.x + threadIdx.x;
  int f = tid & (FF - 1);
  int n = tid >> 7;  // /128
  if (n >= NN) return;

  const float* p1 = x1 + ((size_t)n * 2 * NL1) * FF + f;
  const float* p2 = x2 + ((size_t)n * 2 * NL2) * FF + f;

  float as[NL1], ad[NL1], bs[NL2], bd[NL2];
#pragma unroll
  for (int i = 0; i < NL1; i++) {
    float e = p1[i * FF];
    float o = p1[(NL1 + i) * FF];
    as[i] = 0.5f * (e + o);
    ad[i] = 0.5f * (e - o);
  }
#pragma unroll
  for (int j = 0; j < NL2; j++) {
    float e = p2[j * FF];
    float o = p2[(NL2 + j) * FF];
    bs[j] = e + o;
    bd[j] = e - o;
  }

  float s[NL3], d[NL3];
#pragma unroll
  for (int k = 0; k < NL3; k++) { s[k] = 0.f; d[k] = 0.f; }

#pragma unroll
  for (int i = 0; i < NL1; i++) {
#pragma unroll
    for (int j = 0; j < NL2; j++) {
      float ps = as[i] * bs[j];
      float pd = ad[i] * bd[j];
      int lo = LOF[i] - LOF[j]; if (lo < 0) lo = -lo;
      int hi = LOF[i] + LOF[j];
#pragma unroll
      for (int k = 0; k < NL3; k++) {
        if (LOF3[k] >= lo && LOF3[k] <= hi) {   // compile-time after unroll
          float c = cg[(i * NL2 + j) * NL3 + k]; // uniform -> s_load
          s[k] = fmaf(c, ps, s[k]);
          d[k] = fmaf(c, pd, d[k]);
        }
      }
    }
  }

  float* po = out + ((size_t)n * 2 * NL3) * FF + f;
#pragma unroll
  for (int k = 0; k < NL3; k++) {
    po[k * FF]          = s[k] + d[k];  // even
    po[(NL3 + k) * FF]  = s[k] - d[k];  // odd
  }
}

extern "C" void kernel_launch(void* const* d_in, const int* in_sizes, int n_in,
                              void* d_out, int out_size, void* d_ws, size_t ws_size,
                              hipStream_t stream) {
  const float* x1 = (const float*)d_in[0];
  const float* x2 = (const float*)d_in[1];
  const float* cg = (const float*)d_in[2];
  float* out = (float*)d_out;
  int total = NN * FF;              // 6,400,000 threads, one per (n,f)
  dim3 block(256);
  dim3 grid((total + 255) / 256);   // 25000 blocks
  tp_kernel<<<grid, block, 0, stream>>>(x1, x2, cg, out);
}